// Round 9
// baseline (305.980 us; speedup 1.0000x reference)
//
#include <hip/hip_runtime.h>
#include <hip/hip_bf16.h>

// GATNet: 2-layer GAT, N=50000, E=1.6M (+self loops), f32 inputs (dtype
// auto-detected as insurance), f32 accumulate, bf16/f16 gather tables.
// R9: scat_write rebuilt as LDS full-chunk partition -> per-bucket coalesced
// burst write-out (kills ~16x write amplification of 4B scatters);
// per-block histograms (512 chunks); detect folded into repack.

#define NN 50000
#define NE 1600000
#define NBK 196            // buckets of 256 nodes
#define NB_SC 512          // scatter blocks == chunks
#define CHUNK (NE / NB_SC) // 3125, exact
#define GB1 782            // gemm1 blocks = ceil(NN/64)
#define GB2 1563           // calc_a1 blocks = ceil(NN*8/256)

typedef __attribute__((ext_vector_type(8))) short bf16x8;
typedef __attribute__((ext_vector_type(4))) float f32x4;

__device__ __forceinline__ float lrelu(float x) { return fmaxf(x, 0.2f * x); }

__device__ __forceinline__ float ldf(const void* p, int i, int isbf) {
  return isbf ? __bfloat162float(((const __hip_bfloat16*)p)[i])
              : ((const float*)p)[i];
}
__device__ __forceinline__ short f2bf_bits(float v) {
  __hip_bfloat16 h = __float2bfloat16(v);
  return *reinterpret_cast<short*>(&h);
}
__device__ __forceinline__ float bfs2f(short b) {
  unsigned int u = ((unsigned int)(unsigned short)b) << 16;
  union { unsigned int u; float f; } c; c.u = u; return c.f;
}
__device__ __forceinline__ unsigned short f2h_bits(float v) {
  _Float16 h = (_Float16)v;
  return *reinterpret_cast<unsigned short*>(&h);
}
__device__ __forceinline__ float h2f(unsigned short b) {
  _Float16 h = *reinterpret_cast<_Float16*>(&b);
  return (float)h;
}

// ---------- workspace layout (bytes) ----------
#define OFF_H1   ((size_t)0)           // [NN*128] bf16 (12.8 MB)
#define OFF_H    ((size_t)25600000)    // bf16 Hb [NN*128]; EPp u32[NE] aliases pre-agg1
#define OFF_H2   ((size_t)51200000)    // f16 H2 [NN*16]; HB int[NB_SC*NBK] aliases pre-gemm2
#define OFF_AS1  ((size_t)54400000)    // [NN*8]   f32
#define OFF_AD1  ((size_t)56000000)    // [NN*8]   f32
#define OFF_AS2  ((size_t)57600000)    // [NN]     f32
#define OFF_AD2  ((size_t)57800000)    // [NN]     f32
#define OFF_CNT  ((size_t)58000000)    // [NN]     i32
#define OFF_OFFS ((size_t)58400000)    // [NN]     i32
#define OFF_CSR  ((size_t)58600000)    // [NE]     u16 (3.2 MB)
#define OFF_WP1  ((size_t)65000000)    // [32768]  bf16 (repacked W1)
#define OFF_BCNT ((size_t)65065536)    // [256] i32 (bucket totals)
#define OFF_BBASE ((size_t)65066560)   // [256] i32
#define OFF_FLAG ((size_t)65068608)    // [1]   i32  (1 = bf16, 0 = f32)

// ---------- W1 repack + inline dtype sniff (block 0 publishes FLAG) ----------
__global__ void repack_w1(const void* __restrict__ W1, short* __restrict__ Wp,
                          const unsigned int* __restrict__ xw, int* __restrict__ flag) {
  __shared__ int s[256];
  __shared__ int sf;
  int t = threadIdx.x;
  unsigned int w = xw[t * 97 + 5];
  unsigned int e = (w >> 7) & 0xFF;
  s[t] = (e >= 116 && e <= 138) ? 1 : 0;
  __syncthreads();
  for (int off = 128; off > 0; off >>= 1) {
    if (t < off) s[t] += s[t + off];
    __syncthreads();
  }
  if (t == 0) {
    sf = (s[0] >= 128) ? 1 : 0;
    if (blockIdx.x == 0) *flag = sf;
  }
  __syncthreads();
  int f = sf;
  int i = blockIdx.x * 256 + t;
  int j = i & 7, q = (i >> 3) & 3, c = (i >> 5) & 127, tt = i >> 12;
  int src = (tt * 32 + q * 8 + j) * 128 + c;
  Wp[i] = f ? ((const short*)W1)[src] : f2bf_bits(((const float*)W1)[src]);
}

// ---------- FAT1: gemm1 (blocks 0..GB1-1) || block-hist (blocks GB1..) ------
__global__ __launch_bounds__(256) void fat1(const void* __restrict__ X,
                                            const short* __restrict__ Wp,
                                            short* __restrict__ H1b,
                                            const int* __restrict__ flag,
                                            const int* __restrict__ dst,
                                            int* __restrict__ HB) {
  __shared__ int h[224];
  if (blockIdx.x < GB1) {
    // ---- gemm1: h1 = x @ W1, native dtype in, bf16 out ----
    int wave = threadIdx.x >> 6, lane = threadIdx.x & 63;
    int rowbase = blockIdx.x * 64 + wave * 16;
    int l15 = lane & 15, quad = lane >> 4;
    int f = *flag;
    int arow = rowbase + l15;
    if (arow >= NN) arow = NN - 1;
    f32x4 acc[8];
#pragma unroll
    for (int ct = 0; ct < 8; ++ct) acc[ct] = (f32x4){0.f, 0.f, 0.f, 0.f};
    size_t abase = (size_t)arow * 256 + quad * 8;
#pragma unroll
    for (int kt = 0; kt < 8; ++kt) {
      bf16x8 a;
      if (f) {
        a = *(const bf16x8*)((const short*)X + abase + kt * 32);
      } else {
        const float* xp = (const float*)X + abase + kt * 32;
        float4 v0 = *(const float4*)xp, v1 = *(const float4*)(xp + 4);
        a[0] = f2bf_bits(v0.x); a[1] = f2bf_bits(v0.y);
        a[2] = f2bf_bits(v0.z); a[3] = f2bf_bits(v0.w);
        a[4] = f2bf_bits(v1.x); a[5] = f2bf_bits(v1.y);
        a[6] = f2bf_bits(v1.z); a[7] = f2bf_bits(v1.w);
      }
#pragma unroll
      for (int ct = 0; ct < 8; ++ct) {
        bf16x8 b = *(const bf16x8*)(Wp + ((kt * 128 + ct * 16 + l15) * 4 + quad) * 8);
        acc[ct] = __builtin_amdgcn_mfma_f32_16x16x32_bf16(a, b, acc[ct], 0, 0, 0);
      }
    }
    int r0 = rowbase + quad * 4;
#pragma unroll
    for (int ct = 0; ct < 8; ++ct)
#pragma unroll
      for (int r = 0; r < 4; ++r) {
        int row = r0 + r;
        if (row < NN) H1b[(size_t)row * 128 + ct * 16 + l15] = f2bf_bits(acc[ct][r]);
      }
  } else {
    // ---- per-block bucket histogram ----
    int b = blockIdx.x - GB1;
    int t = threadIdx.x;
    for (int i = t; i < 224; i += 256) h[i] = 0;
    __syncthreads();
    int e0 = b * CHUNK, e1 = e0 + CHUNK;
    for (int e = e0 + t; e < e1; e += 256) atomicAdd(&h[dst[e] >> 8], 1);
    __syncthreads();
    for (int i = t; i < NBK; i += 256) HB[b * NBK + i] = h[i];
  }
}

// ---------- FAT2: calc_a1 (blocks 0..GB2-1) || scan1 (blocks GB2..) ---------
__global__ __launch_bounds__(256) void fat2(const short* __restrict__ H1b,
                                            const void* __restrict__ as1,
                                            const void* __restrict__ ad1,
                                            float* __restrict__ AS,
                                            float* __restrict__ AD,
                                            const int* __restrict__ flag,
                                            int* __restrict__ HB,
                                            int* __restrict__ total) {
  __shared__ float s_as[128], s_ad[128];
  __shared__ int ts[256];
  int t = threadIdx.x;
  if (blockIdx.x < GB2) {
    int f = *flag;
    if (t < 128) { s_as[t] = ldf(as1, t, f); s_ad[t] = ldf(ad1, t, f); }
    __syncthreads();
    int tid = blockIdx.x * 256 + t;
    if (tid >= NN * 8) return;
    int n = tid >> 3, hh = tid & 7;
    const bf16x8* hp = (const bf16x8*)(H1b + (size_t)n * 128 + hh * 16);
    bf16x8 v0 = hp[0], v1 = hp[1];
    float as = 0.f, ad = 0.f;
#pragma unroll
    for (int i = 0; i < 8; ++i) {
      int b = hh * 16 + i;
      float x0 = bfs2f(v0[i]), x1 = bfs2f(v1[i]);
      as += x0 * s_as[b] + x1 * s_as[b + 8];
      ad += x0 * s_ad[b] + x1 * s_ad[b + 8];
    }
    AS[tid] = as; AD[tid] = ad;
  } else {
    // per-bucket exclusive scan over NB_SC chunks (thread t owns 2)
    int k = blockIdx.x - GB2;
    int v0 = HB[(t * 2) * NBK + k], v1 = HB[(t * 2 + 1) * NBK + k];
    int s = v0 + v1;
    ts[t] = s;
    __syncthreads();
    for (int off = 1; off < 256; off <<= 1) {
      int a = (t >= off) ? ts[t - off] : 0;
      __syncthreads();
      ts[t] += a;
      __syncthreads();
    }
    int ex = ts[t] - s;
    HB[(t * 2) * NBK + k] = ex;
    HB[(t * 2 + 1) * NBK + k] = ex + v0;
    if (t == 255) total[k] = ts[255];
  }
}

// ---------- scan bucket totals ----------
__global__ void scat_scan2(const int* __restrict__ total, int* __restrict__ bbase,
                           int* __restrict__ bcnt) {
  __shared__ int sd[256];
  int t = threadIdx.x;
  int v = (t < NBK) ? total[t] : 0;
  sd[t] = v;
  __syncthreads();
  for (int off = 1; off < 256; off <<= 1) {
    int a = (t >= off) ? sd[t - off] : 0;
    __syncthreads();
    sd[t] += a;
    __syncthreads();
  }
  if (t < NBK) { bbase[t] = sd[t] - v; bcnt[t] = v; }
}

// ---------- scat_write v2: LDS full-chunk partition + coalesced burst out ---
// EPp word: bits 16..23 = node-in-bucket (dst & 255), bits 0..15 = src (<65536)
__global__ __launch_bounds__(256) void scat_write(const int* __restrict__ src,
                                                  const int* __restrict__ dst,
                                                  const int* __restrict__ HB,
                                                  const int* __restrict__ bbase,
                                                  unsigned int* __restrict__ EPp) {
  __shared__ int h[224], sc[256], lofs[224], lc[224], gd[224];
  __shared__ unsigned int EB[CHUNK];
  int t = threadIdx.x, b = blockIdx.x;
  for (int i = t; i < 224; i += 256) h[i] = 0;
  __syncthreads();
  int e0 = b * CHUNK, e1 = e0 + CHUNK;
  for (int e = e0 + t; e < e1; e += 256) atomicAdd(&h[dst[e] >> 8], 1);
  __syncthreads();
  int v = (t < NBK) ? h[t] : 0;
  sc[t] = v;
  __syncthreads();
  for (int off = 1; off < 256; off <<= 1) {
    int a = (t >= off) ? sc[t - off] : 0;
    __syncthreads();
    sc[t] += a;
    __syncthreads();
  }
  if (t < NBK) {
    int ex = sc[t] - v;
    lofs[t] = ex; lc[t] = ex;
    gd[t] = bbase[t] + HB[b * NBK + t];
  }
  __syncthreads();
  for (int e = e0 + t; e < e1; e += 256) {
    int d = dst[e];
    int pos = atomicAdd(&lc[d >> 8], 1);
    EB[pos] = ((unsigned int)(d & 255) << 16) | (unsigned int)src[e];
  }
  __syncthreads();
  for (int k = 0; k < NBK; ++k) {
    int len = h[k];
    if (!len) continue;
    int g0 = gd[k], l0 = lofs[k];
    for (int i = t; i < len; i += 256) EPp[g0 + i] = EB[l0 + i];
  }
}

// ---------- per-bucket LDS CSR (1024 threads, ushort output) ----------
__global__ __launch_bounds__(1024) void bucket_csr(const unsigned int* __restrict__ EPp,
                                                   const int* __restrict__ bcnt,
                                                   const int* __restrict__ bbase,
                                                   int* __restrict__ cnt,
                                                   int* __restrict__ offs,
                                                   unsigned short* __restrict__ csr) {
  __shared__ int h[256], sc[256], lc[256];
  int b = blockIdx.x, t = threadIdx.x;
  int gbase = bbase[b], n = bcnt[b];
  if (t < 256) h[t] = 0;
  __syncthreads();
  for (int i = t; i < n; i += 1024) atomicAdd(&h[(EPp[gbase + i] >> 16) & 255], 1);
  __syncthreads();
  int v = 0;
  if (t < 256) { v = h[t]; sc[t] = v; }
  __syncthreads();
  for (int off = 1; off < 256; off <<= 1) {
    int add = (t >= off && t < 256) ? sc[t - off] : 0;
    __syncthreads();
    if (t < 256) sc[t] += add;
    __syncthreads();
  }
  if (t < 256) {
    int ex = sc[t] - v;
    int node = (b << 8) + t;
    if (node < NN) { cnt[node] = v; offs[node] = gbase + ex; }
    lc[t] = ex;
  }
  __syncthreads();
  for (int i = t; i < n; i += 1024) {
    unsigned int p = EPp[gbase + i];
    int pos = atomicAdd(&lc[(p >> 16) & 255], 1);
    csr[gbase + pos] = (unsigned short)(p & 0xFFFF);
  }
}

// ---------- layer-1 softmax + aggregate: one wave per dst node --------------
__global__ __launch_bounds__(256) void agg1(const short* __restrict__ H1b,
                                            const float* __restrict__ AS,
                                            const float* __restrict__ AD,
                                            const int* __restrict__ offs,
                                            const int* __restrict__ cnt,
                                            const unsigned short* __restrict__ csr,
                                            const void* __restrict__ bias1,
                                            short* __restrict__ Hb,
                                            const int* __restrict__ flag) {
  int lane = threadIdx.x & 63;
  int node = blockIdx.x * 4 + (threadIdx.x >> 6);
  int f = *flag;
  int start = offs[node], deg = cnt[node];
  int g = lane >> 3, k = lane & 7;
  float adst = AD[node * 8 + k];
  float acc[16];
#pragma unroll
  for (int i = 0; i < 16; ++i) acc[i] = 0.f;
  float dsum = 0.f;
  if (g == 0) {
    float p = __expf(lrelu(AS[node * 8 + k] + adst));
    dsum = p;
    const bf16x8* hp = (const bf16x8*)(H1b + (size_t)node * 128 + k * 16);
    bf16x8 v0 = hp[0], v1 = hp[1];
#pragma unroll
    for (int i = 0; i < 8; ++i) {
      acc[i] = p * bfs2f(v0[i]);
      acc[8 + i] = p * bfs2f(v1[i]);
    }
  }
  int s = (g < deg) ? (int)csr[start + g] : -1;
  float a_c = 0.f; bf16x8 v0, v1;
  if (s >= 0) {
    a_c = AS[s * 8 + k];
    const bf16x8* hp = (const bf16x8*)(H1b + (size_t)s * 128 + k * 16);
    v0 = hp[0]; v1 = hp[1];
  }
  for (int eb = 0; eb < deg; eb += 8) {
    int en = eb + 8 + g;
    int sn = (en < deg) ? (int)csr[start + en] : -1;
    float a_n = 0.f; bf16x8 w0, w1;
    if (sn >= 0) {
      a_n = AS[sn * 8 + k];
      const bf16x8* hp = (const bf16x8*)(H1b + (size_t)sn * 128 + k * 16);
      w0 = hp[0]; w1 = hp[1];
    }
    if (s >= 0) {
      float p = __expf(lrelu(a_c + adst));
      dsum += p;
#pragma unroll
      for (int i = 0; i < 8; ++i) {
        acc[i] += p * bfs2f(v0[i]);
        acc[8 + i] += p * bfs2f(v1[i]);
      }
    }
    s = sn; a_c = a_n; v0 = w0; v1 = w1;
  }
#pragma unroll
  for (int i = 0; i < 16; ++i) {
    acc[i] += __shfl_xor(acc[i], 8);
    acc[i] += __shfl_xor(acc[i], 16);
    acc[i] += __shfl_xor(acc[i], 32);
  }
  dsum += __shfl_xor(dsum, 8);
  dsum += __shfl_xor(dsum, 16);
  dsum += __shfl_xor(dsum, 32);
  if (g == 0) {
    float inv = 1.0f / dsum;
    int c0 = k * 16;
    bf16x8 o0, o1;
#pragma unroll
    for (int i = 0; i < 8; ++i) {
      o0[i] = f2bf_bits(fmaxf(acc[i] * inv + ldf(bias1, c0 + i, f), 0.f));
      o1[i] = f2bf_bits(fmaxf(acc[8 + i] * inv + ldf(bias1, c0 + 8 + i, f), 0.f));
    }
    *(bf16x8*)(Hb + (size_t)node * 128 + c0) = o0;
    *(bf16x8*)(Hb + (size_t)node * 128 + c0 + 8) = o1;
  }
}

// ---------- GEMM2 (128->16, bf16 in, f16 H2 out) + fused a_src2/a_dst2 ------
__global__ __launch_bounds__(256) void gemm2_a2(const short* __restrict__ Hb,
                                                const void* __restrict__ W2,
                                                const void* __restrict__ as2,
                                                const void* __restrict__ ad2,
                                                unsigned short* __restrict__ H2h,
                                                float* __restrict__ AS2,
                                                float* __restrict__ AD2,
                                                const int* __restrict__ flag) {
  __shared__ float sW[2048];
  __shared__ float s_as[16], s_ad[16];
  int t = threadIdx.x;
  int f = *flag;
  for (int i = t; i < 2048; i += 256) sW[i] = ldf(W2, i, f);
  if (t < 16) { s_as[t] = ldf(as2, t, f); s_ad[t] = ldf(ad2, t, f); }
  __syncthreads();
  int n = blockIdx.x * 16 + (t >> 4), c = t & 15;  // 3125*16 == NN exactly
  const bf16x8* hp = (const bf16x8*)(Hb + (size_t)n * 128);
  float acc = 0.f;
#pragma unroll 4
  for (int k8 = 0; k8 < 16; ++k8) {
    bf16x8 v = hp[k8];
#pragma unroll
    for (int i = 0; i < 8; ++i) acc += bfs2f(v[i]) * sW[(k8 * 8 + i) * 16 + c];
  }
  H2h[n * 16 + c] = f2h_bits(acc);
  float vs = acc * s_as[c], vd = acc * s_ad[c];
#pragma unroll
  for (int off = 1; off < 16; off <<= 1) {
    vs += __shfl_xor(vs, off);
    vd += __shfl_xor(vd, off);
  }
  if (c == 0) { AS2[n] = vs; AD2[n] = vd; }
}

// ---------- layer-2 softmax + aggregate (f16 table, pipelined) --------------
__global__ __launch_bounds__(256) void agg2(const unsigned short* __restrict__ H2h,
                                            const float* __restrict__ AS2,
                                            const float* __restrict__ AD2,
                                            const int* __restrict__ offs,
                                            const int* __restrict__ cnt,
                                            const unsigned short* __restrict__ csr,
                                            const void* __restrict__ bias2,
                                            void* __restrict__ outv,
                                            const int* __restrict__ flag) {
  int lane = threadIdx.x & 63;
  int node = blockIdx.x * 4 + (threadIdx.x >> 6);
  int f = *flag;
  int start = offs[node], deg = cnt[node];
  int g = lane >> 3, k = lane & 7;
  float adst = AD2[node];
  float a0 = 0.f, a1 = 0.f, dsum = 0.f;
  if (g == 0) {
    float p = __expf(lrelu(AS2[node] + adst));
    dsum = p;
    unsigned int hv = *(const unsigned int*)(H2h + (size_t)node * 16 + k * 2);
    a0 = p * h2f((unsigned short)(hv & 0xFFFF));
    a1 = p * h2f((unsigned short)(hv >> 16));
  }
  int s = (g < deg) ? (int)csr[start + g] : -1;
  float as_c = 0.f; unsigned int hv_c = 0;
  if (s >= 0) {
    as_c = AS2[s];
    hv_c = *(const unsigned int*)(H2h + (size_t)s * 16 + k * 2);
  }
  for (int eb = 0; eb < deg; eb += 8) {
    int en = eb + 8 + g;
    int sn = (en < deg) ? (int)csr[start + en] : -1;
    float as_n = 0.f; unsigned int hv_n = 0;
    if (sn >= 0) {
      as_n = AS2[sn];
      hv_n = *(const unsigned int*)(H2h + (size_t)sn * 16 + k * 2);
    }
    if (s >= 0) {
      float p = __expf(lrelu(as_c + adst));
      dsum += p;
      a0 += p * h2f((unsigned short)(hv_c & 0xFFFF));
      a1 += p * h2f((unsigned short)(hv_c >> 16));
    }
    s = sn; as_c = as_n; hv_c = hv_n;
  }
  a0 += __shfl_xor(a0, 8);  a0 += __shfl_xor(a0, 16);  a0 += __shfl_xor(a0, 32);
  a1 += __shfl_xor(a1, 8);  a1 += __shfl_xor(a1, 16);  a1 += __shfl_xor(a1, 32);
  dsum += __shfl_xor(dsum, 8); dsum += __shfl_xor(dsum, 16); dsum += __shfl_xor(dsum, 32);
  if (g == 0) {
    float inv = 1.0f / dsum;
    float o0 = a0 * inv + ldf(bias2, k * 2 + 0, f);
    float o1 = a1 * inv + ldf(bias2, k * 2 + 1, f);
    size_t base = (size_t)node * 16 + k * 2;
    if (f) {
      ((__hip_bfloat16*)outv)[base] = __float2bfloat16(o0);
      ((__hip_bfloat16*)outv)[base + 1] = __float2bfloat16(o1);
    } else {
      *(float2*)((float*)outv + base) = make_float2(o0, o1);
    }
  }
}

extern "C" void kernel_launch(void* const* d_in, const int* in_sizes, int n_in,
                              void* d_out, int out_size, void* d_ws, size_t ws_size,
                              hipStream_t stream) {
  const void* x = d_in[0];             // [NN,256]
  const int* ei = (const int*)d_in[1]; // [2,NE] i32
  const void* W1 = d_in[2];            // [256,128]
  const void* as1 = d_in[3];
  const void* ad1 = d_in[4];
  const void* b1 = d_in[5];
  const void* W2 = d_in[6];            // [128,16]
  const void* as2 = d_in[7];
  const void* ad2 = d_in[8];
  const void* b2 = d_in[9];
  char* ws = (char*)d_ws;

  short* H1b = (short*)(ws + OFF_H1);
  short* Hb = (short*)(ws + OFF_H);            // bf16 layer-1 output
  unsigned int* EPp = (unsigned int*)(ws + OFF_H);  // aliases Hb (dead pre-agg1)
  unsigned short* H2h = (unsigned short*)(ws + OFF_H2);
  int* HB = (int*)(ws + OFF_H2);               // aliases H2h (dead pre-gemm2)
  float* AS1 = (float*)(ws + OFF_AS1);
  float* AD1 = (float*)(ws + OFF_AD1);
  float* AS2 = (float*)(ws + OFF_AS2);
  float* AD2 = (float*)(ws + OFF_AD2);
  int* CNT = (int*)(ws + OFF_CNT);
  int* OFFS = (int*)(ws + OFF_OFFS);
  unsigned short* CSR = (unsigned short*)(ws + OFF_CSR);
  short* Wp = (short*)(ws + OFF_WP1);
  int* BCNT = (int*)(ws + OFF_BCNT);
  int* BBASE = (int*)(ws + OFF_BBASE);
  int* FLAG = (int*)(ws + OFF_FLAG);

  repack_w1<<<128, 256, 0, stream>>>(W1, Wp, (const unsigned int*)x, FLAG);
  fat1<<<GB1 + NB_SC, 256, 0, stream>>>(x, Wp, H1b, FLAG, ei + NE, HB);
  fat2<<<GB2 + NBK, 256, 0, stream>>>(H1b, as1, ad1, AS1, AD1, FLAG, HB, BCNT);
  scat_scan2<<<1, 256, 0, stream>>>(BCNT, BBASE, BCNT);
  scat_write<<<NB_SC, 256, 0, stream>>>(ei, ei + NE, HB, BBASE, EPp);
  bucket_csr<<<NBK, 1024, 0, stream>>>(EPp, BCNT, BBASE, CNT, OFFS, CSR);

  agg1<<<NN / 4, 256, 0, stream>>>(H1b, AS1, AD1, OFFS, CNT, CSR, b1, Hb, FLAG);
  gemm2_a2<<<NN / 16, 256, 0, stream>>>(Hb, W2, as2, ad2, H2h, AS2, AD2, FLAG);
  agg2<<<NN / 4, 256, 0, stream>>>(H2h, AS2, AD2, OFFS, CNT, CSR, b2, d_out, FLAG);
}

// Round 10
// 273.424 us; speedup vs baseline: 1.1191x; 1.1191x over previous
//
#include <hip/hip_runtime.h>
#include <hip/hip_bf16.h>

// GATNet: 2-layer GAT, N=50000, E=1.6M (+self loops), f32 inputs (dtype
// auto-detected as insurance), f32 accumulate, bf16/f16 gather tables.
// R10: scat_write v3 — LDS partition + FLAT parallel burst write-out
// (R9's serial 196-bucket loop was the regression); scat_scan2 dispatch
// deleted (consumers recompute the 196-entry scan in-block).

#define NN 50000
#define NE 1600000
#define NBK 196            // buckets of 256 nodes
#define NB_SC 512          // scatter blocks == chunks
#define CHUNK (NE / NB_SC) // 3125, exact
#define GB1 782            // gemm1 blocks = ceil(NN/64)
#define GB2 1563           // calc_a1 blocks = ceil(NN*8/256)

typedef __attribute__((ext_vector_type(8))) short bf16x8;
typedef __attribute__((ext_vector_type(4))) float f32x4;

__device__ __forceinline__ float lrelu(float x) { return fmaxf(x, 0.2f * x); }

__device__ __forceinline__ float ldf(const void* p, int i, int isbf) {
  return isbf ? __bfloat162float(((const __hip_bfloat16*)p)[i])
              : ((const float*)p)[i];
}
__device__ __forceinline__ short f2bf_bits(float v) {
  __hip_bfloat16 h = __float2bfloat16(v);
  return *reinterpret_cast<short*>(&h);
}
__device__ __forceinline__ float bfs2f(short b) {
  unsigned int u = ((unsigned int)(unsigned short)b) << 16;
  union { unsigned int u; float f; } c; c.u = u; return c.f;
}
__device__ __forceinline__ unsigned short f2h_bits(float v) {
  _Float16 h = (_Float16)v;
  return *reinterpret_cast<unsigned short*>(&h);
}
__device__ __forceinline__ float h2f(unsigned short b) {
  _Float16 h = *reinterpret_cast<_Float16*>(&b);
  return (float)h;
}

// ---------- workspace layout (bytes) ----------
#define OFF_H1   ((size_t)0)           // [NN*128] bf16 (12.8 MB)
#define OFF_H    ((size_t)25600000)    // bf16 Hb [NN*128]; EPp u32[NE] aliases pre-agg1
#define OFF_H2   ((size_t)51200000)    // f16 H2 [NN*16]; HB int[NB_SC*NBK] aliases pre-gemm2
#define OFF_AS1  ((size_t)54400000)    // [NN*8]   f32
#define OFF_AD1  ((size_t)56000000)    // [NN*8]   f32
#define OFF_AS2  ((size_t)57600000)    // [NN]     f32
#define OFF_AD2  ((size_t)57800000)    // [NN]     f32
#define OFF_CNT  ((size_t)58000000)    // [NN]     i32
#define OFF_OFFS ((size_t)58400000)    // [NN]     i32
#define OFF_CSR  ((size_t)58600000)    // [NE]     u16 (3.2 MB)
#define OFF_WP1  ((size_t)65000000)    // [32768]  bf16 (repacked W1)
#define OFF_TOT  ((size_t)65065536)    // [256] i32 (bucket totals)
#define OFF_FLAG ((size_t)65068608)    // [1]   i32  (1 = bf16, 0 = f32)

// ---------- W1 repack + inline dtype sniff (block 0 publishes FLAG) ----------
__global__ void repack_w1(const void* __restrict__ W1, short* __restrict__ Wp,
                          const unsigned int* __restrict__ xw, int* __restrict__ flag) {
  __shared__ int s[256];
  __shared__ int sf;
  int t = threadIdx.x;
  unsigned int w = xw[t * 97 + 5];
  unsigned int e = (w >> 7) & 0xFF;
  s[t] = (e >= 116 && e <= 138) ? 1 : 0;
  __syncthreads();
  for (int off = 128; off > 0; off >>= 1) {
    if (t < off) s[t] += s[t + off];
    __syncthreads();
  }
  if (t == 0) {
    sf = (s[0] >= 128) ? 1 : 0;
    if (blockIdx.x == 0) *flag = sf;
  }
  __syncthreads();
  int f = sf;
  int i = blockIdx.x * 256 + t;
  int j = i & 7, q = (i >> 3) & 3, c = (i >> 5) & 127, tt = i >> 12;
  int src = (tt * 32 + q * 8 + j) * 128 + c;
  Wp[i] = f ? ((const short*)W1)[src] : f2bf_bits(((const float*)W1)[src]);
}

// ---------- FAT1: gemm1 (blocks 0..GB1-1) || block-hist (blocks GB1..) ------
__global__ __launch_bounds__(256) void fat1(const void* __restrict__ X,
                                            const short* __restrict__ Wp,
                                            short* __restrict__ H1b,
                                            const int* __restrict__ flag,
                                            const int* __restrict__ dst,
                                            int* __restrict__ HB) {
  __shared__ int h[224];
  if (blockIdx.x < GB1) {
    // ---- gemm1: h1 = x @ W1, native dtype in, bf16 out ----
    int wave = threadIdx.x >> 6, lane = threadIdx.x & 63;
    int rowbase = blockIdx.x * 64 + wave * 16;
    int l15 = lane & 15, quad = lane >> 4;
    int f = *flag;
    int arow = rowbase + l15;
    if (arow >= NN) arow = NN - 1;
    f32x4 acc[8];
#pragma unroll
    for (int ct = 0; ct < 8; ++ct) acc[ct] = (f32x4){0.f, 0.f, 0.f, 0.f};
    size_t abase = (size_t)arow * 256 + quad * 8;
#pragma unroll
    for (int kt = 0; kt < 8; ++kt) {
      bf16x8 a;
      if (f) {
        a = *(const bf16x8*)((const short*)X + abase + kt * 32);
      } else {
        const float* xp = (const float*)X + abase + kt * 32;
        float4 v0 = *(const float4*)xp, v1 = *(const float4*)(xp + 4);
        a[0] = f2bf_bits(v0.x); a[1] = f2bf_bits(v0.y);
        a[2] = f2bf_bits(v0.z); a[3] = f2bf_bits(v0.w);
        a[4] = f2bf_bits(v1.x); a[5] = f2bf_bits(v1.y);
        a[6] = f2bf_bits(v1.z); a[7] = f2bf_bits(v1.w);
      }
#pragma unroll
      for (int ct = 0; ct < 8; ++ct) {
        bf16x8 b = *(const bf16x8*)(Wp + ((kt * 128 + ct * 16 + l15) * 4 + quad) * 8);
        acc[ct] = __builtin_amdgcn_mfma_f32_16x16x32_bf16(a, b, acc[ct], 0, 0, 0);
      }
    }
    int r0 = rowbase + quad * 4;
#pragma unroll
    for (int ct = 0; ct < 8; ++ct)
#pragma unroll
      for (int r = 0; r < 4; ++r) {
        int row = r0 + r;
        if (row < NN) H1b[(size_t)row * 128 + ct * 16 + l15] = f2bf_bits(acc[ct][r]);
      }
  } else {
    // ---- per-block bucket histogram ----
    int b = blockIdx.x - GB1;
    int t = threadIdx.x;
    for (int i = t; i < 224; i += 256) h[i] = 0;
    __syncthreads();
    int e0 = b * CHUNK, e1 = e0 + CHUNK;
    for (int e = e0 + t; e < e1; e += 256) atomicAdd(&h[dst[e] >> 8], 1);
    __syncthreads();
    for (int i = t; i < NBK; i += 256) HB[b * NBK + i] = h[i];
  }
}

// ---------- FAT2: calc_a1 (blocks 0..GB2-1) || scan1 (blocks GB2..) ---------
__global__ __launch_bounds__(256) void fat2(const short* __restrict__ H1b,
                                            const void* __restrict__ as1,
                                            const void* __restrict__ ad1,
                                            float* __restrict__ AS,
                                            float* __restrict__ AD,
                                            const int* __restrict__ flag,
                                            int* __restrict__ HB,
                                            int* __restrict__ total) {
  __shared__ float s_as[128], s_ad[128];
  __shared__ int ts[256];
  int t = threadIdx.x;
  if (blockIdx.x < GB2) {
    int f = *flag;
    if (t < 128) { s_as[t] = ldf(as1, t, f); s_ad[t] = ldf(ad1, t, f); }
    __syncthreads();
    int tid = blockIdx.x * 256 + t;
    if (tid >= NN * 8) return;
    int n = tid >> 3, hh = tid & 7;
    const bf16x8* hp = (const bf16x8*)(H1b + (size_t)n * 128 + hh * 16);
    bf16x8 v0 = hp[0], v1 = hp[1];
    float as = 0.f, ad = 0.f;
#pragma unroll
    for (int i = 0; i < 8; ++i) {
      int b = hh * 16 + i;
      float x0 = bfs2f(v0[i]), x1 = bfs2f(v1[i]);
      as += x0 * s_as[b] + x1 * s_as[b + 8];
      ad += x0 * s_ad[b] + x1 * s_ad[b + 8];
    }
    AS[tid] = as; AD[tid] = ad;
  } else {
    // per-bucket exclusive scan over NB_SC chunks (thread t owns 2);
    // HB entries become within-bucket exclusive chunk offsets.
    int k = blockIdx.x - GB2;
    int v0 = HB[(t * 2) * NBK + k], v1 = HB[(t * 2 + 1) * NBK + k];
    int s = v0 + v1;
    ts[t] = s;
    __syncthreads();
    for (int off = 1; off < 256; off <<= 1) {
      int a = (t >= off) ? ts[t - off] : 0;
      __syncthreads();
      ts[t] += a;
      __syncthreads();
    }
    int ex = ts[t] - s;
    HB[(t * 2) * NBK + k] = ex;
    HB[(t * 2 + 1) * NBK + k] = ex + v0;
    if (t == 255) total[k] = ts[255];
  }
}

// ---------- scat_write v3: LDS partition + flat parallel burst write-out ----
// EPp word: bits 16..23 = node-in-bucket (dst & 255), bits 0..15 = src (<65536)
__global__ __launch_bounds__(256) void scat_write(const int* __restrict__ src,
                                                  const int* __restrict__ dst,
                                                  const int* __restrict__ HB,
                                                  const int* __restrict__ total,
                                                  unsigned int* __restrict__ EPp) {
  __shared__ int h[224], sc[256], lofs[224], lc[224], gd[224];
  __shared__ unsigned int EB[CHUNK];
  __shared__ unsigned char BKT[CHUNK];
  int t = threadIdx.x, b = blockIdx.x;
  // in-block exclusive scan of bucket totals -> global bucket bases
  int tv = (t < NBK) ? total[t] : 0;
  sc[t] = tv;
  __syncthreads();
  for (int off = 1; off < 256; off <<= 1) {
    int a = (t >= off) ? sc[t - off] : 0;
    __syncthreads();
    sc[t] += a;
    __syncthreads();
  }
  if (t < NBK) gd[t] = (sc[t] - tv) + HB[b * NBK + t];  // bbase + my chunk offset
  for (int i = t; i < 224; i += 256) h[i] = 0;
  __syncthreads();
  int e0 = b * CHUNK, e1 = e0 + CHUNK;
  for (int e = e0 + t; e < e1; e += 256) atomicAdd(&h[dst[e] >> 8], 1);
  __syncthreads();
  int v = (t < NBK) ? h[t] : 0;
  sc[t] = v;
  __syncthreads();
  for (int off = 1; off < 256; off <<= 1) {
    int a = (t >= off) ? sc[t - off] : 0;
    __syncthreads();
    sc[t] += a;
    __syncthreads();
  }
  if (t < NBK) { int ex = sc[t] - v; lofs[t] = ex; lc[t] = ex; }
  __syncthreads();
  // partition into LDS, remembering each position's bucket
  for (int e = e0 + t; e < e1; e += 256) {
    int d = dst[e];
    int k = d >> 8;
    int pos = atomicAdd(&lc[k], 1);
    EB[pos] = ((unsigned int)(d & 255) << 16) | (unsigned int)src[e];
    BKT[pos] = (unsigned char)k;
  }
  __syncthreads();
  // flat write-out: consecutive pos -> consecutive global within bucket runs
  for (int pos = t; pos < CHUNK; pos += 256) {
    int k = BKT[pos];
    EPp[gd[k] + (pos - lofs[k])] = EB[pos];
  }
}

// ---------- per-bucket LDS CSR (1024 threads, ushort output) ----------
__global__ __launch_bounds__(1024) void bucket_csr(const unsigned int* __restrict__ EPp,
                                                   const int* __restrict__ total,
                                                   int* __restrict__ cnt,
                                                   int* __restrict__ offs,
                                                   unsigned short* __restrict__ csr) {
  __shared__ int h[256], sc[256], lc[256];
  int b = blockIdx.x, t = threadIdx.x;
  // in-block scan of totals -> this bucket's base
  int tv = 0;
  if (t < 256) { tv = (t < NBK) ? total[t] : 0; sc[t] = tv; }
  __syncthreads();
  for (int off = 1; off < 256; off <<= 1) {
    int a = (t >= off && t < 256) ? sc[t - off] : 0;
    __syncthreads();
    if (t < 256) sc[t] += a;
    __syncthreads();
  }
  __shared__ int s_gbase, s_n;
  if (t == (unsigned)b) { s_gbase = sc[b] - tv; s_n = tv; }
  __syncthreads();
  int gbase = s_gbase, n = s_n;
  if (t < 256) h[t] = 0;
  __syncthreads();
  for (int i = t; i < n; i += 1024) atomicAdd(&h[(EPp[gbase + i] >> 16) & 255], 1);
  __syncthreads();
  int v = 0;
  if (t < 256) { v = h[t]; sc[t] = v; }
  __syncthreads();
  for (int off = 1; off < 256; off <<= 1) {
    int add = (t >= off && t < 256) ? sc[t - off] : 0;
    __syncthreads();
    if (t < 256) sc[t] += add;
    __syncthreads();
  }
  if (t < 256) {
    int ex = sc[t] - v;
    int node = (b << 8) + t;
    if (node < NN) { cnt[node] = v; offs[node] = gbase + ex; }
    lc[t] = ex;
  }
  __syncthreads();
  for (int i = t; i < n; i += 1024) {
    unsigned int p = EPp[gbase + i];
    int pos = atomicAdd(&lc[(p >> 16) & 255], 1);
    csr[gbase + pos] = (unsigned short)(p & 0xFFFF);
  }
}

// ---------- layer-1 softmax + aggregate: one wave per dst node --------------
__global__ __launch_bounds__(256) void agg1(const short* __restrict__ H1b,
                                            const float* __restrict__ AS,
                                            const float* __restrict__ AD,
                                            const int* __restrict__ offs,
                                            const int* __restrict__ cnt,
                                            const unsigned short* __restrict__ csr,
                                            const void* __restrict__ bias1,
                                            short* __restrict__ Hb,
                                            const int* __restrict__ flag) {
  int lane = threadIdx.x & 63;
  int node = blockIdx.x * 4 + (threadIdx.x >> 6);
  int f = *flag;
  int start = offs[node], deg = cnt[node];
  int g = lane >> 3, k = lane & 7;
  float adst = AD[node * 8 + k];
  float acc[16];
#pragma unroll
  for (int i = 0; i < 16; ++i) acc[i] = 0.f;
  float dsum = 0.f;
  if (g == 0) {
    float p = __expf(lrelu(AS[node * 8 + k] + adst));
    dsum = p;
    const bf16x8* hp = (const bf16x8*)(H1b + (size_t)node * 128 + k * 16);
    bf16x8 v0 = hp[0], v1 = hp[1];
#pragma unroll
    for (int i = 0; i < 8; ++i) {
      acc[i] = p * bfs2f(v0[i]);
      acc[8 + i] = p * bfs2f(v1[i]);
    }
  }
  int s = (g < deg) ? (int)csr[start + g] : -1;
  float a_c = 0.f; bf16x8 v0, v1;
  if (s >= 0) {
    a_c = AS[s * 8 + k];
    const bf16x8* hp = (const bf16x8*)(H1b + (size_t)s * 128 + k * 16);
    v0 = hp[0]; v1 = hp[1];
  }
  for (int eb = 0; eb < deg; eb += 8) {
    int en = eb + 8 + g;
    int sn = (en < deg) ? (int)csr[start + en] : -1;
    float a_n = 0.f; bf16x8 w0, w1;
    if (sn >= 0) {
      a_n = AS[sn * 8 + k];
      const bf16x8* hp = (const bf16x8*)(H1b + (size_t)sn * 128 + k * 16);
      w0 = hp[0]; w1 = hp[1];
    }
    if (s >= 0) {
      float p = __expf(lrelu(a_c + adst));
      dsum += p;
#pragma unroll
      for (int i = 0; i < 8; ++i) {
        acc[i] += p * bfs2f(v0[i]);
        acc[8 + i] += p * bfs2f(v1[i]);
      }
    }
    s = sn; a_c = a_n; v0 = w0; v1 = w1;
  }
#pragma unroll
  for (int i = 0; i < 16; ++i) {
    acc[i] += __shfl_xor(acc[i], 8);
    acc[i] += __shfl_xor(acc[i], 16);
    acc[i] += __shfl_xor(acc[i], 32);
  }
  dsum += __shfl_xor(dsum, 8);
  dsum += __shfl_xor(dsum, 16);
  dsum += __shfl_xor(dsum, 32);
  if (g == 0) {
    float inv = 1.0f / dsum;
    int c0 = k * 16;
    bf16x8 o0, o1;
#pragma unroll
    for (int i = 0; i < 8; ++i) {
      o0[i] = f2bf_bits(fmaxf(acc[i] * inv + ldf(bias1, c0 + i, f), 0.f));
      o1[i] = f2bf_bits(fmaxf(acc[8 + i] * inv + ldf(bias1, c0 + 8 + i, f), 0.f));
    }
    *(bf16x8*)(Hb + (size_t)node * 128 + c0) = o0;
    *(bf16x8*)(Hb + (size_t)node * 128 + c0 + 8) = o1;
  }
}

// ---------- GEMM2 (128->16, bf16 in, f16 H2 out) + fused a_src2/a_dst2 ------
__global__ __launch_bounds__(256) void gemm2_a2(const short* __restrict__ Hb,
                                                const void* __restrict__ W2,
                                                const void* __restrict__ as2,
                                                const void* __restrict__ ad2,
                                                unsigned short* __restrict__ H2h,
                                                float* __restrict__ AS2,
                                                float* __restrict__ AD2,
                                                const int* __restrict__ flag) {
  __shared__ float sW[2048];
  __shared__ float s_as[16], s_ad[16];
  int t = threadIdx.x;
  int f = *flag;
  for (int i = t; i < 2048; i += 256) sW[i] = ldf(W2, i, f);
  if (t < 16) { s_as[t] = ldf(as2, t, f); s_ad[t] = ldf(ad2, t, f); }
  __syncthreads();
  int n = blockIdx.x * 16 + (t >> 4), c = t & 15;  // 3125*16 == NN exactly
  const bf16x8* hp = (const bf16x8*)(Hb + (size_t)n * 128);
  float acc = 0.f;
#pragma unroll 4
  for (int k8 = 0; k8 < 16; ++k8) {
    bf16x8 v = hp[k8];
#pragma unroll
    for (int i = 0; i < 8; ++i) acc += bfs2f(v[i]) * sW[(k8 * 8 + i) * 16 + c];
  }
  H2h[n * 16 + c] = f2h_bits(acc);
  float vs = acc * s_as[c], vd = acc * s_ad[c];
#pragma unroll
  for (int off = 1; off < 16; off <<= 1) {
    vs += __shfl_xor(vs, off);
    vd += __shfl_xor(vd, off);
  }
  if (c == 0) { AS2[n] = vs; AD2[n] = vd; }
}

// ---------- layer-2 softmax + aggregate (f16 table, pipelined) --------------
__global__ __launch_bounds__(256) void agg2(const unsigned short* __restrict__ H2h,
                                            const float* __restrict__ AS2,
                                            const float* __restrict__ AD2,
                                            const int* __restrict__ offs,
                                            const int* __restrict__ cnt,
                                            const unsigned short* __restrict__ csr,
                                            const void* __restrict__ bias2,
                                            void* __restrict__ outv,
                                            const int* __restrict__ flag) {
  int lane = threadIdx.x & 63;
  int node = blockIdx.x * 4 + (threadIdx.x >> 6);
  int f = *flag;
  int start = offs[node], deg = cnt[node];
  int g = lane >> 3, k = lane & 7;
  float adst = AD2[node];
  float a0 = 0.f, a1 = 0.f, dsum = 0.f;
  if (g == 0) {
    float p = __expf(lrelu(AS2[node] + adst));
    dsum = p;
    unsigned int hv = *(const unsigned int*)(H2h + (size_t)node * 16 + k * 2);
    a0 = p * h2f((unsigned short)(hv & 0xFFFF));
    a1 = p * h2f((unsigned short)(hv >> 16));
  }
  int s = (g < deg) ? (int)csr[start + g] : -1;
  float as_c = 0.f; unsigned int hv_c = 0;
  if (s >= 0) {
    as_c = AS2[s];
    hv_c = *(const unsigned int*)(H2h + (size_t)s * 16 + k * 2);
  }
  for (int eb = 0; eb < deg; eb += 8) {
    int en = eb + 8 + g;
    int sn = (en < deg) ? (int)csr[start + en] : -1;
    float as_n = 0.f; unsigned int hv_n = 0;
    if (sn >= 0) {
      as_n = AS2[sn];
      hv_n = *(const unsigned int*)(H2h + (size_t)sn * 16 + k * 2);
    }
    if (s >= 0) {
      float p = __expf(lrelu(as_c + adst));
      dsum += p;
      a0 += p * h2f((unsigned short)(hv_c & 0xFFFF));
      a1 += p * h2f((unsigned short)(hv_c >> 16));
    }
    s = sn; as_c = as_n; hv_c = hv_n;
  }
  a0 += __shfl_xor(a0, 8);  a0 += __shfl_xor(a0, 16);  a0 += __shfl_xor(a0, 32);
  a1 += __shfl_xor(a1, 8);  a1 += __shfl_xor(a1, 16);  a1 += __shfl_xor(a1, 32);
  dsum += __shfl_xor(dsum, 8); dsum += __shfl_xor(dsum, 16); dsum += __shfl_xor(dsum, 32);
  if (g == 0) {
    float inv = 1.0f / dsum;
    float o0 = a0 * inv + ldf(bias2, k * 2 + 0, f);
    float o1 = a1 * inv + ldf(bias2, k * 2 + 1, f);
    size_t base = (size_t)node * 16 + k * 2;
    if (f) {
      ((__hip_bfloat16*)outv)[base] = __float2bfloat16(o0);
      ((__hip_bfloat16*)outv)[base + 1] = __float2bfloat16(o1);
    } else {
      *(float2*)((float*)outv + base) = make_float2(o0, o1);
    }
  }
}

extern "C" void kernel_launch(void* const* d_in, const int* in_sizes, int n_in,
                              void* d_out, int out_size, void* d_ws, size_t ws_size,
                              hipStream_t stream) {
  const void* x = d_in[0];             // [NN,256]
  const int* ei = (const int*)d_in[1]; // [2,NE] i32
  const void* W1 = d_in[2];            // [256,128]
  const void* as1 = d_in[3];
  const void* ad1 = d_in[4];
  const void* b1 = d_in[5];
  const void* W2 = d_in[6];            // [128,16]
  const void* as2 = d_in[7];
  const void* ad2 = d_in[8];
  const void* b2 = d_in[9];
  char* ws = (char*)d_ws;

  short* H1b = (short*)(ws + OFF_H1);
  short* Hb = (short*)(ws + OFF_H);            // bf16 layer-1 output
  unsigned int* EPp = (unsigned int*)(ws + OFF_H);  // aliases Hb (dead pre-agg1)
  unsigned short* H2h = (unsigned short*)(ws + OFF_H2);
  int* HB = (int*)(ws + OFF_H2);               // aliases H2h (dead pre-gemm2)
  float* AS1 = (float*)(ws + OFF_AS1);
  float* AD1 = (float*)(ws + OFF_AD1);
  float* AS2 = (float*)(ws + OFF_AS2);
  float* AD2 = (float*)(ws + OFF_AD2);
  int* CNT = (int*)(ws + OFF_CNT);
  int* OFFS = (int*)(ws + OFF_OFFS);
  unsigned short* CSR = (unsigned short*)(ws + OFF_CSR);
  short* Wp = (short*)(ws + OFF_WP1);
  int* TOT = (int*)(ws + OFF_TOT);
  int* FLAG = (int*)(ws + OFF_FLAG);

  repack_w1<<<128, 256, 0, stream>>>(W1, Wp, (const unsigned int*)x, FLAG);
  fat1<<<GB1 + NB_SC, 256, 0, stream>>>(x, Wp, H1b, FLAG, ei + NE, HB);
  fat2<<<GB2 + NBK, 256, 0, stream>>>(H1b, as1, ad1, AS1, AD1, FLAG, HB, TOT);
  scat_write<<<NB_SC, 256, 0, stream>>>(ei, ei + NE, HB, TOT, EPp);
  bucket_csr<<<NBK, 1024, 0, stream>>>(EPp, TOT, CNT, OFFS, CSR);

  agg1<<<NN / 4, 256, 0, stream>>>(H1b, AS1, AD1, OFFS, CNT, CSR, b1, Hb, FLAG);
  gemm2_a2<<<NN / 16, 256, 0, stream>>>(Hb, W2, as2, ad2, H2h, AS2, AD2, FLAG);
  agg2<<<NN / 4, 256, 0, stream>>>(H2h, AS2, AD2, OFFS, CNT, CSR, b2, d_out, FLAG);
}